// Round 8
// baseline (280.527 us; speedup 1.0000x reference)
//
#include <hip/hip_runtime.h>
#include <math.h>

// ToyPredictor: h' = tanh(h @ W_hh^T + xt*v + c);  y = h'.W_out + b_out
// v = W_xh @ W_in, c = W_xh @ b_in + b_h  (precomputed on device)
// B=4096, T=512 (511 steps), DIM=128.
//
// Round-8: BREAK THE BARRIER LOCKSTEP. r7 counters show pipes summing
// (port+VALU+MFMA ~= step time): the block-wide barrier re-syncs all waves
// every step. Fix: 512 blocks x 256 thr (__launch_bounds__(256,2)) -> TWO
// independent 8-batch recurrences per CU with separate barriers; each SIMD
// hosts 2 waves from DIFFERENT blocks, so one block's compute overlaps the
// other's read-latency/barrier. B-frag cols 8-15 are pad (zero-init, stays
// tanh-bounded); MFMA work doubles but stays far below the port time.
// + T5 setprio(1) around the MFMA cluster (cross-block role diversity).
// Numerics identical to r7 on real columns (hi/lo W, single-plane bf16 h).

#define DIM    128
#define TFULL  512
#define TS     511
#define ROWS   8
#define NTHR   256
#define NBLK   512   // 4096 / 8 rows per block
#define SEQPAD 9

typedef __attribute__((ext_vector_type(8))) short short8;
typedef __attribute__((ext_vector_type(4))) float f32x4;

static __device__ __forceinline__ unsigned short bf16_rne(float x) {
  unsigned u = __float_as_uint(x);
  u += 0x7fffu + ((u >> 16) & 1u);
  return (unsigned short)(u >> 16);
}

__global__ void precompute_vc(const float* __restrict__ W_in,
                              const float* __restrict__ b_in,
                              const float* __restrict__ W_xh,
                              const float* __restrict__ b_h,
                              float* __restrict__ ws) {
  const int i = threadIdx.x;   // 128 threads
  float v = 0.f, c = 0.f;
  for (int j = 0; j < DIM; ++j) {
    const float wx = W_xh[i * DIM + j];
    v = fmaf(wx, W_in[j], v);
    c = fmaf(wx, b_in[j], c);
  }
  ws[i] = v;
  ws[DIM + i] = c + b_h[i];
  if (i == 0) ws[2 * DIM] = 0.f;   // zero sse accumulator every launch
}

__global__ __launch_bounds__(NTHR, 2)
void helical_fwd(const float* __restrict__ seq,     // [4096,512]
                 const float* __restrict__ W_hh,    // [128,128]
                 const float* __restrict__ W_out,   // [1,128]
                 const float* __restrict__ b_out,   // [1]
                 const float* __restrict__ ws,      // v[128], c[128]
                 float* __restrict__ sse_accum,     // [1]
                 float* __restrict__ preds) {       // [4096,511]
  // S: fragment-linear, single bf16 plane, 2 buffers (4 KiB each).
  //   byte(b,k) = (k>>5)*1024 + phys(ln)*16 + (k&7)*2,
  //   ln = b + 16*((k>>3)&3), phys = ln ^ (ln>>3).
  // cols b: 0-7 real batch, 8-15 pad (tanh-bounded garbage).
  __shared__ __align__(16) unsigned short Sh[2][2048];    // 8 KiB
  __shared__ __align__(16) float seqT[TFULL * SEQPAD];    // 18 KiB

  const int tid  = threadIdx.x;
  const int w    = tid >> 6;     // wave 0..3 (owns dims 32w .. 32w+31)
  const int lane = tid & 63;
  const int l15  = lane & 15;    // B/C col (batch; >=8 pad)
  const int lk   = lane >> 4;    // 0..3
  const int row0 = blockIdx.x * ROWS;
  char* SB = (char*)Sh;

  // Stage seq transposed: seqT[t*SEQPAD + b] = seq[row0+b][t], b<8.
  {
    const float4* src = (const float4*)(seq + (size_t)row0 * TFULL);
#pragma unroll
    for (int k0 = 0; k0 < 4; ++k0) {
      const int k = tid + k0 * NTHR;         // 1024 float4 total
      const float4 v = src[k];
      const int r  = k >> 7;                 // 0..7
      const int t0 = (k & 127) << 2;
      seqT[(t0 + 0) * SEQPAD + r] = v.x;
      seqT[(t0 + 1) * SEQPAD + r] = v.y;
      seqT[(t0 + 2) * SEQPAD + r] = v.z;
      seqT[(t0 + 3) * SEQPAD + r] = v.w;
    }
  }
  // S0 = 0 (both real and pad cols): zero buf0 (4096 B).
  {
    uint4 z; z.x = z.y = z.z = z.w = 0u;
    ((uint4*)SB)[tid] = z;
  }

  // A-frags, tile tt of wave w: wH/wL[tt][kk][e] = split of
  //   W[32w+16tt+l15][32kk+8lk+e].
  short8 wH[2][4], wL[2][4];
  float vr[2][4], cr[2][4];
#pragma unroll
  for (int tt = 0; tt < 2; ++tt) {
    const int rowW = 32 * w + 16 * tt + l15;
    const float* wr = W_hh + (size_t)rowW * DIM + 8 * lk;
#pragma unroll
    for (int kk = 0; kk < 4; ++kk) {
      float f[8];
      const float4 p0 = *(const float4*)(wr + 32 * kk);
      const float4 p1 = *(const float4*)(wr + 32 * kk + 4);
      f[0] = p0.x; f[1] = p0.y; f[2] = p0.z; f[3] = p0.w;
      f[4] = p1.x; f[5] = p1.y; f[6] = p1.z; f[7] = p1.w;
#pragma unroll
      for (int e = 0; e < 8; ++e) {
        const unsigned short h = bf16_rne(f[e]);
        const float hf = __uint_as_float((unsigned)h << 16);
        wH[tt][kk][e] = (short)h;
        wL[tt][kk][e] = (short)bf16_rne(f[e] - hf);
      }
    }
    const int dbase = 32 * w + 16 * tt + 4 * lk;
#pragma unroll
    for (int r = 0; r < 4; ++r) {
      vr[tt][r] = ws[dbase + r];
      cr[tt][r] = ws[DIM + dbase + r];
    }
  }
  // W_out as A-frag row 0 (hi+lo), every wave (rotating owner).
  short8 woH[4], woL[4];
#pragma unroll
  for (int kk = 0; kk < 4; ++kk) {
#pragma unroll
    for (int e = 0; e < 8; ++e) {
      const float f = (l15 == 0) ? W_out[32 * kk + 8 * lk + e] : 0.f;
      const unsigned short h = bf16_rne(f);
      const float hf = __uint_as_float((unsigned)h << 16);
      woH[kk][e] = (short)h;
      woL[kk][e] = (short)bf16_rne(f - hf);
    }
  }
  const float bout = b_out[0];

  // Reads: contiguous-permuted 16B per lane (conflict-free, r3-proven).
  const int rdb = (lane ^ (lane >> 3)) << 4;
  // Writes: one 8B slot per lane per tile (2-way bank pairs = free, r5).
  const int lnw0 = l15 | ((lk >> 1) << 4);          // tt=0
  const int lnw1 = l15 | ((2 + (lk >> 1)) << 4);    // tt=1
  const int wB0 = (w << 10) + ((lnw0 ^ (lnw0 >> 3)) << 4) + ((lk & 1) << 3);
  const int wB1 = (w << 10) + ((lnw1 ^ (lnw1 >> 3)) << 4) + ((lk & 1) << 3);

  const f32x4 ZERO = {0.f, 0.f, 0.f, 0.f};
  const float K2LOG2E = 2.8853900817779268f;   // 2*log2(e)
  float sse = 0.f;
  int xadr = l15 & 7;
  const int pidx_b = (row0 + (l15 & 7)) * TS;

  __syncthreads();

#define STEP(CUR, DOFIN, TPRED)                                                \
  {                                                                            \
    const float xtb = seqT[xadr];                                              \
    xadr += SEQPAD;                                                            \
    short8 sH[4];                                                              \
    _Pragma("unroll")                                                          \
    for (int kk = 0; kk < 4; ++kk)                                             \
      sH[kk] = *(const short8*)(SB + (CUR)*4096 + kk*1024 + rdb);              \
    f32x4 p[2], q[2];                                                          \
    _Pragma("unroll")                                                          \
    for (int tt = 0; tt < 2; ++tt) {                                           \
      p[tt][0] = fmaf(xtb, vr[tt][0], cr[tt][0]);                              \
      p[tt][1] = fmaf(xtb, vr[tt][1], cr[tt][1]);                              \
      p[tt][2] = fmaf(xtb, vr[tt][2], cr[tt][2]);                              \
      p[tt][3] = fmaf(xtb, vr[tt][3], cr[tt][3]);                              \
    }                                                                          \
    const bool own = (DOFIN) && (w == ((TPRED) & 3));                          \
    __builtin_amdgcn_s_setprio(1);                                             \
    _Pragma("unroll")                                                          \
    for (int kk = 0; kk < 4; ++kk) {                                           \
      _Pragma("unroll")                                                        \
      for (int tt = 0; tt < 2; ++tt) {                                         \
        p[tt] = __builtin_amdgcn_mfma_f32_16x16x32_bf16(wH[tt][kk], sH[kk], p[tt], 0, 0, 0); \
        q[tt] = __builtin_amdgcn_mfma_f32_16x16x32_bf16(wL[tt][kk], sH[kk],    \
                    kk ? q[tt] : ZERO, 0, 0, 0);                               \
      }                                                                        \
    }                                                                          \
    f32x4 y1, y2;                                                              \
    if (own) {                                                                 \
      _Pragma("unroll")                                                        \
      for (int kk = 0; kk < 4; ++kk) {                                         \
        y1 = __builtin_amdgcn_mfma_f32_16x16x32_bf16(woH[kk], sH[kk],          \
                 kk ? y1 : ZERO, 0, 0, 0);                                     \
        y2 = __builtin_amdgcn_mfma_f32_16x16x32_bf16(woL[kk], sH[kk],          \
                 kk ? y2 : ZERO, 0, 0, 0);                                     \
      }                                                                        \
    }                                                                          \
    __builtin_amdgcn_s_setprio(0);                                             \
    _Pragma("unroll")                                                          \
    for (int tt = 0; tt < 2; ++tt) {                                           \
      const f32x4 pre = p[tt] + q[tt];                                         \
      float th[4];                                                             \
      _Pragma("unroll")                                                        \
      for (int r = 0; r < 4; ++r) {                                            \
        const float ag = pre[r] * K2LOG2E;                                     \
        float ex;                                                              \
        asm("v_exp_f32 %0, %1" : "=v"(ex) : "v"(ag));                          \
        const float rc = __builtin_amdgcn_rcpf(ex + 1.f);                      \
        th[r] = fmaf(-2.f, rc, 1.f);                                           \
      }                                                                        \
      uint2 hv;                                                                \
      asm("v_cvt_pk_bf16_f32 %0, %1, %2" : "=v"(hv.x) : "v"(th[0]), "v"(th[1])); \
      asm("v_cvt_pk_bf16_f32 %0, %1, %2" : "=v"(hv.y) : "v"(th[2]), "v"(th[3])); \
      *(uint2*)(SB + ((CUR) ^ 1) * 4096 + (tt ? wB1 : wB0)) = hv;              \
    }                                                                          \
    if (own && lane < 8) {                                                     \
      const float y = y1[0] + y2[0] + bout;                                    \
      preds[pidx_b + (TPRED)] = y;                                             \
      const float d = y - xtb;                                                 \
      sse = fmaf(d, d, sse);                                                   \
    }                                                                          \
    asm volatile("s_waitcnt lgkmcnt(0)" ::: "memory");                         \
    __builtin_amdgcn_s_barrier();                                              \
    asm volatile("" ::: "memory");                                             \
  }

  STEP(0, false, 0)                     // iter 0: h0 -> h1, no pred yet
  for (int tq = 0; tq < 255; ++tq) {
    STEP(1, true, 2 * tq)               // iter 2tq+1: pred[2tq] from h_{2tq+1}
    STEP(0, true, 2 * tq + 1)           // iter 2tq+2: pred[2tq+1]
  }
#undef STEP

  // Tail: pred[510] from h_511 (buf 1); target seq[:,511] at xadr.
  if (w == 2) {   // owner = 510 & 3
    short8 sH[4];
#pragma unroll
    for (int kk = 0; kk < 4; ++kk)
      sH[kk] = *(const short8*)(SB + 4096 + kk * 1024 + rdb);
    f32x4 y1, y2;
#pragma unroll
    for (int kk = 0; kk < 4; ++kk) {
      y1 = __builtin_amdgcn_mfma_f32_16x16x32_bf16(woH[kk], sH[kk],
               kk ? y1 : ZERO, 0, 0, 0);
      y2 = __builtin_amdgcn_mfma_f32_16x16x32_bf16(woL[kk], sH[kk],
               kk ? y2 : ZERO, 0, 0, 0);
    }
    if (lane < 8) {
      const float xf = seqT[xadr];
      const float y = y1[0] + y2[0] + bout;
      preds[pidx_b + 510] = y;
      const float d = y - xf;
      sse = fmaf(d, d, sse);
    }
  }
  // Per-wave sse (lanes 0-7) -> one atomicAdd per wave.
  float s = (lane < 8) ? sse : 0.f;
  s += __shfl_xor(s, 1);
  s += __shfl_xor(s, 2);
  s += __shfl_xor(s, 4);
  if (lane == 0) atomicAdd(sse_accum, s);
}

__global__ void finalize_loss(const float* __restrict__ sse,
                              float* __restrict__ out) {
  out[(size_t)4096 * TS] = sse[0] * (1.0f / (4096.0f * (float)TS));
}

extern "C" void kernel_launch(void* const* d_in, const int* in_sizes, int n_in,
                              void* d_out, int out_size, void* d_ws, size_t ws_size,
                              hipStream_t stream) {
  const float* seq   = (const float*)d_in[0];
  const float* W_in  = (const float*)d_in[1];
  const float* b_in  = (const float*)d_in[2];
  const float* W_hh  = (const float*)d_in[3];
  const float* W_xh  = (const float*)d_in[4];
  const float* b_h   = (const float*)d_in[5];
  const float* W_out = (const float*)d_in[6];
  const float* b_out = (const float*)d_in[7];
  float* out = (float*)d_out;
  float* ws  = (float*)d_ws;   // ws[0..127]=v, ws[128..255]=c, ws[256]=sse

  precompute_vc<<<1, DIM, 0, stream>>>(W_in, b_in, W_xh, b_h, ws);
  helical_fwd<<<NBLK, NTHR, 0, stream>>>(seq, W_hh, W_out, b_out, ws,
                                         ws + 2 * DIM, out);
  finalize_loss<<<1, 1, 0, stream>>>(ws + 2 * DIM, out);
}